// Round 5
// baseline (403.956 us; speedup 1.0000x reference)
//
#include <hip/hip_runtime.h>
#include <math.h>

#define NSRC 32768
#define NTOT 65536
#define NDST 32768
#define DH   256

typedef __attribute__((ext_vector_type(8))) short bf16x8;
typedef __attribute__((ext_vector_type(4))) float f32x4;

__device__ __forceinline__ float wave_reduce(float v) {
#pragma unroll
  for (int off = 32; off > 0; off >>= 1) v += __shfl_xor(v, off, 64);
  return v;
}
__device__ __forceinline__ unsigned short f2bf(float f) {
  union { float f; unsigned u; } v; v.f = f;
  unsigned r = v.u + 0x7FFFu + ((v.u >> 16) & 1u);
  return (unsigned short)(r >> 16);
}
__device__ __forceinline__ float bf2f(unsigned short h) {
  union { unsigned u; float f; } v; v.u = ((unsigned)h) << 16;
  return v.f;
}
__device__ __forceinline__ float4 bf4(ushort4 v) {
  return make_float4(bf2f(v.x), bf2f(v.y), bf2f(v.z), bf2f(v.w));
}
__device__ __forceinline__ void add4(float4& a, const float4 v) {
  a.x += v.x; a.y += v.y; a.z += v.z; a.w += v.w;
}
__device__ __forceinline__ float dot4(const float4 a, const float4 b) {
  return a.x * b.x + a.y * b.y + a.z * b.z + a.w * b.w;
}
// hsrc value: prelu(v + b) * isc
__device__ __forceinline__ float4 hsrc4(const float4 v, const float4 bv,
                                        float alpha, float isc) {
  float4 h;
  h.x = v.x + bv.x; h.x = (h.x >= 0.f ? h.x : alpha * h.x) * isc;
  h.y = v.y + bv.y; h.y = (h.y >= 0.f ? h.y : alpha * h.y) * isc;
  h.z = v.z + bv.z; h.z = (h.z >= 0.f ? h.z : alpha * h.z) * isc;
  h.w = v.w + bv.w; h.w = (h.w >= 0.f ? h.w : alpha * h.w) * isc;
  return h;
}

// ---------------- W -> Wt (transpose + bf16) --------------------------------
__global__ __launch_bounds__(256) void k_cvtW(const float* __restrict__ W,
                                              unsigned short* __restrict__ Wt) {
  const int n = blockIdx.x, k = threadIdx.x;
  Wt[n * 256 + k] = f2bf(W[(size_t)k * 256 + n]);
}

// ---------------- MFMA GEMM, N-split x2 for occupancy -----------------------
// grid 2048: rowgrp=(bid&7)|((bid>>4)<<3), nhalf=(bid>>3)&1 (feat-sharing
// blocks are 8 apart -> same XCD -> L2 reuse of the feat strip).
__global__ __launch_bounds__(256) void k_gemm_mfma(
    const float* __restrict__ A, const unsigned short* __restrict__ Wt,
    unsigned short* __restrict__ mb) {
  const int bid = blockIdx.x;
  const int rowgrp = (bid & 7) | ((bid >> 4) << 3);
  const int nhalf = (bid >> 3) & 1;
  const int t = threadIdx.x;
  const int lane = t & 63;
  const int wv = t >> 6;
  const int ln = lane & 15;
  const int kq = lane >> 4;          // 0..3
  const int row = rowgrp * 64 + wv * 16 + ln;

  bf16x8 bs[8];
  const float* ap = A + (size_t)row * 256 + kq * 8;
#pragma unroll
  for (int ks = 0; ks < 8; ++ks) {
    float4 a0 = *(const float4*)(ap + ks * 32);
    float4 a1 = *(const float4*)(ap + ks * 32 + 4);
    bf16x8 v;
    v[0] = (short)f2bf(a0.x); v[1] = (short)f2bf(a0.y);
    v[2] = (short)f2bf(a0.z); v[3] = (short)f2bf(a0.w);
    v[4] = (short)f2bf(a1.x); v[5] = (short)f2bf(a1.y);
    v[6] = (short)f2bf(a1.z); v[7] = (short)f2bf(a1.w);
    bs[ks] = v;
  }

  f32x4 acc[8];
#pragma unroll
  for (int i = 0; i < 8; ++i) acc[i] = (f32x4){0.f, 0.f, 0.f, 0.f};

  const int nt0 = nhalf * 8;
#pragma unroll
  for (int nt = 0; nt < 8; ++nt) {
    const unsigned short* wp = Wt + (size_t)((nt0 + nt) * 16 + ln) * 256 + kq * 8;
#pragma unroll
    for (int ks = 0; ks < 8; ++ks) {
      bf16x8 af = *(const bf16x8*)(wp + ks * 32);
      acc[nt] = __builtin_amdgcn_mfma_f32_16x16x32_bf16(af, bs[ks], acc[nt], 0, 0, 0);
    }
  }

  const int n0 = kq * 4;
#pragma unroll
  for (int nt = 0; nt < 8; ++nt) {
    ushort4 o;
    o.x = f2bf(acc[nt][0]); o.y = f2bf(acc[nt][1]);
    o.z = f2bf(acc[nt][2]); o.w = f2bf(acc[nt][3]);
    *(ushort4*)(mb + (size_t)row * 256 + (nt0 + nt) * 16 + n0) = o;
  }
}

// ---------------- per-src-row inverse norm of prelu(m+b) --------------------
__global__ __launch_bounds__(256) void k_inn(const unsigned short* __restrict__ mb,
                                             const float* __restrict__ b,
                                             const float* __restrict__ pa,
                                             float* __restrict__ inn) {
  const int row = blockIdx.x * 4 + (threadIdx.x >> 6);
  const int lane = threadIdx.x & 63;
  const int c = lane * 4;
  float4 v = bf4(*(const ushort4*)(mb + (size_t)row * 256 + c));
  float4 bv = *(const float4*)(b + c);
  const float alpha = pa[0];
  float4 h = hsrc4(v, bv, alpha, 1.0f);
  float ss = wave_reduce(dot4(h, h));
  if (lane == 0) inn[row] = 1.0f / fmaxf(sqrtf(ss), 1e-8f);
}

// ---------------- CSR build --------------------------------------------------
__global__ __launch_bounds__(256) void k_deg(const int* __restrict__ dst,
                                             int* __restrict__ deg, int nE) {
  const int e = blockIdx.x * 256 + threadIdx.x;
  if (e < nE) atomicAdd(&deg[dst[e] - NSRC], 1);
}

__global__ __launch_bounds__(256) void k_scan(const int* __restrict__ deg,
                                              int* __restrict__ rowStart) {
  __shared__ int tot[256];
  const int t = threadIdx.x;
  const int base = t * 128;
  int s = 0;
  for (int i = 0; i < 128; ++i) s += deg[base + i];
  tot[t] = s;
  __syncthreads();
  for (int off = 1; off < 256; off <<= 1) {
    int v = (t >= off) ? tot[t - off] : 0;
    __syncthreads();
    tot[t] += v;
    __syncthreads();
  }
  int pre = (t == 0) ? 0 : tot[t - 1];
  for (int i = 0; i < 128; ++i) {
    rowStart[base + i] = pre;
    pre += deg[base + i];
  }
  if (t == 255) rowStart[NDST] = pre;
}

__global__ __launch_bounds__(256) void k_fill(const int* __restrict__ src,
                                              const int* __restrict__ dst,
                                              const int* __restrict__ rowStart,
                                              int* __restrict__ cur,
                                              int* __restrict__ eSrc, int nE) {
  const int e = blockIdx.x * 256 + threadIdx.x;
  if (e >= nE) return;
  const int d = dst[e] - NSRC;
  const int p = atomicAdd(&cur[d], 1);
  eSrc[rowStart[d] + p] = src[e];
}

// ---------------- neg-subset claim matching (neg edges sub-multiset of pos) -
__global__ __launch_bounds__(256) void k_claim(const int* __restrict__ rsP,
                                               const int* __restrict__ esP,
                                               const int* __restrict__ rsN,
                                               const int* __restrict__ esN,
                                               unsigned char* __restrict__ claim) {
  const int row = blockIdx.x * 256 + threadIdx.x;
  if (row >= NDST) return;
  const int p0 = rsP[row], p1 = rsP[row + 1];
  const int n0 = rsN[row], n1 = rsN[row + 1];
  for (int i = n0; i < n1; ++i) {
    const int s = esN[i];
    for (int j = p0; j < p1; ++j) {
      if (esP[j] == s && claim[j] == 0) { claim[j] = 1; break; }
    }
  }
}

// ---------------- fused: agg(P,N) + prelu + norm + all loss terms -----------
__global__ __launch_bounds__(256) void k_fused(const unsigned short* __restrict__ mb,
                                               const float* __restrict__ inn,
                                               const int* __restrict__ rsP,
                                               const int* __restrict__ esP,
                                               const unsigned char* __restrict__ claim,
                                               const int* __restrict__ rsN,
                                               const float* __restrict__ b,
                                               const float* __restrict__ pa,
                                               float* __restrict__ hraw,
                                               float* __restrict__ sims) {
  const int row = blockIdx.x * 4 + (threadIdx.x >> 6);
  const int lane = threadIdx.x & 63;
  const int c = lane * 4;
  const int p0 = rsP[row], p1 = rsP[row + 1];
  const int cN = rsN[row + 1] - rsN[row];
  const float4 bv = *(const float4*)(b + c);
  const float alpha = pa[0];

  float4 self = bf4(*(const ushort4*)(mb + (size_t)(NSRC + row) * 256 + c));
  float4 aP0 = self, aP1 = {0.f, 0.f, 0.f, 0.f};
  float4 aN0 = self, aN1 = {0.f, 0.f, 0.f, 0.f};
  float4 sP0 = {0.f, 0.f, 0.f, 0.f}, sP1 = {0.f, 0.f, 0.f, 0.f};
  float4 sN0 = {0.f, 0.f, 0.f, 0.f}, sN1 = {0.f, 0.f, 0.f, 0.f};

  int e = p0;
  for (; e + 1 < p1; e += 2) {
    const int s0 = esP[e], s1 = esP[e + 1];
    const int cl0 = claim[e], cl1 = claim[e + 1];
    const float i0 = inn[s0], i1 = inn[s1];
    float4 v0 = bf4(*(const ushort4*)(mb + (size_t)s0 * 256 + c));
    float4 v1 = bf4(*(const ushort4*)(mb + (size_t)s1 * 256 + c));
    float4 h0 = hsrc4(v0, bv, alpha, i0);
    float4 h1 = hsrc4(v1, bv, alpha, i1);
    add4(aP0, v0); add4(sP0, h0);
    add4(aP1, v1); add4(sP1, h1);
    if (cl0) { add4(aN0, v0); add4(sN0, h0); }
    if (cl1) { add4(aN1, v1); add4(sN1, h1); }
  }
  if (e < p1) {
    const int s0 = esP[e];
    const int cl0 = claim[e];
    const float i0 = inn[s0];
    float4 v0 = bf4(*(const ushort4*)(mb + (size_t)s0 * 256 + c));
    float4 h0 = hsrc4(v0, bv, alpha, i0);
    add4(aP0, v0); add4(sP0, h0);
    if (cl0) { add4(aN0, v0); add4(sN0, h0); }
  }
  add4(aP0, aP1); add4(aN0, aN1); add4(sP0, sP1); add4(sN0, sN1);

  const float invP = 1.0f / (float)(p1 - p0 + 1);
  const float invN = 1.0f / (float)(cN + 1);
  float4 hp, hn;
  hp.x = aP0.x * invP + bv.x; hp.x = hp.x >= 0.f ? hp.x : alpha * hp.x;
  hp.y = aP0.y * invP + bv.y; hp.y = hp.y >= 0.f ? hp.y : alpha * hp.y;
  hp.z = aP0.z * invP + bv.z; hp.z = hp.z >= 0.f ? hp.z : alpha * hp.z;
  hp.w = aP0.w * invP + bv.w; hp.w = hp.w >= 0.f ? hp.w : alpha * hp.w;
  hn.x = aN0.x * invN + bv.x; hn.x = hn.x >= 0.f ? hn.x : alpha * hn.x;
  hn.y = aN0.y * invN + bv.y; hn.y = hn.y >= 0.f ? hn.y : alpha * hn.y;
  hn.z = aN0.z * invN + bv.z; hn.z = hn.z >= 0.f ? hn.z : alpha * hn.z;
  hn.w = aN0.w * invN + bv.w; hn.w = hn.w >= 0.f ? hn.w : alpha * hn.w;

  *(float4*)(hraw + (size_t)row * 256 + c) = hp;  // h_pos[NSRC:] output

  float ssP = wave_reduce(dot4(hp, hp));
  float ssN = wave_reduce(dot4(hn, hn));
  const float iP = 1.0f / fmaxf(sqrtf(ssP), 1e-8f);
  const float iN = 1.0f / fmaxf(sqrtf(ssN), 1e-8f);
  float4 xp = hp, xn = hn;
  xp.x *= iP; xp.y *= iP; xp.z *= iP; xp.w *= iP;
  xn.x *= iN; xn.y *= iN; xn.z *= iN; xn.w *= iN;

  float pos = wave_reduce(dot4(xp, xn));
  float n1 = wave_reduce(dot4(xp, sN0));
  float n2 = wave_reduce(dot4(xn, sP0));
  if (lane == 0) {
    sims[row] = pos;
    sims[NDST + row] = pos + n1;       // + self-loop term
    sims[2 * NDST + row] = pos + n2;   // + self-loop term
  }
}

// ---------------- final log-sum-exp reduce ----------------------------------
__global__ __launch_bounds__(256) void k_reduce(const float* __restrict__ sims,
                                                float* __restrict__ red) {
  const int i = blockIdx.x * 256 + threadIdx.x;
  const float v = sims[i];
  float e = expf(v);
  float p = (i < NDST) ? v : 0.f;
  e = wave_reduce(e);
  p = wave_reduce(p);
  __shared__ float se[4], sp[4];
  const int lane = threadIdx.x & 63, w = threadIdx.x >> 6;
  if (lane == 0) { se[w] = e; sp[w] = p; }
  __syncthreads();
  if (threadIdx.x == 0) {
    atomicAdd(red + 0, se[0] + se[1] + se[2] + se[3]);
    atomicAdd(red + 1, sp[0] + sp[1] + sp[2] + sp[3]);
  }
}

__global__ void k_final(const float* __restrict__ red, float* __restrict__ out) {
  out[0] = logf(red[0]) - red[1];
}

extern "C" void kernel_launch(void* const* d_in, const int* in_sizes, int n_in,
                              void* d_out, int out_size, void* d_ws, size_t ws_size,
                              hipStream_t stream) {
  const float* feat = (const float*)d_in[0];
  const int*   src  = (const int*)d_in[1];
  const int*   dst  = (const int*)d_in[2];
  const int*   nsrc = (const int*)d_in[3];
  const int*   ndst = (const int*)d_in[4];
  const float* W    = (const float*)d_in[5];
  const float* b    = (const float*)d_in[6];
  const float* pa   = (const float*)d_in[7];
  const int nE  = in_sizes[1];
  const int nEn = in_sizes[3];
  float* out = (float*)d_out;

  unsigned short* mb = (unsigned short*)d_ws;            // NTOT*256 bf16
  unsigned short* Wt = mb + (size_t)NTOT * 256;          // 256*256 bf16
  float* inn  = (float*)(Wt + 256 * 256);                // NSRC
  float* sims = inn + NSRC;                              // 3*NDST
  float* red  = sims + 3 * (size_t)NDST;                 // 8
  int* degP  = (int*)(red + 8);                          // NDST
  int* curP  = degP + NDST;
  int* degN  = curP + NDST;
  int* curN  = degN + NDST;
  int* rsP   = curN + NDST;                              // NDST+1
  int* rsN   = rsP + NDST + 1;                           // NDST+1
  int* eSrcP = rsN + NDST + 1;                           // nE
  int* eSrcN = eSrcP + nE;                               // nEn
  unsigned char* claim = (unsigned char*)(eSrcN + nEn);  // nE bytes

  hipMemsetAsync(degP, 0, 4 * (size_t)NDST * sizeof(int), stream);
  hipMemsetAsync(red, 0, 8 * sizeof(float), stream);
  hipMemsetAsync(claim, 0, (size_t)nE, stream);

  k_cvtW<<<256, 256, 0, stream>>>(W, Wt);
  k_gemm_mfma<<<2048, 256, 0, stream>>>(feat, Wt, mb);
  k_inn<<<NSRC / 4, 256, 0, stream>>>(mb, b, pa, inn);

  k_deg<<<(nE + 255) / 256, 256, 0, stream>>>(dst, degP, nE);
  k_deg<<<(nEn + 255) / 256, 256, 0, stream>>>(ndst, degN, nEn);
  k_scan<<<1, 256, 0, stream>>>(degP, rsP);
  k_scan<<<1, 256, 0, stream>>>(degN, rsN);
  k_fill<<<(nE + 255) / 256, 256, 0, stream>>>(src, dst, rsP, curP, eSrcP, nE);
  k_fill<<<(nEn + 255) / 256, 256, 0, stream>>>(nsrc, ndst, rsN, curN, eSrcN, nEn);
  k_claim<<<(NDST + 255) / 256, 256, 0, stream>>>(rsP, eSrcP, rsN, eSrcN, claim);

  k_fused<<<NDST / 4, 256, 0, stream>>>(mb, inn, rsP, eSrcP, claim, rsN, b, pa,
                                        out + 1, sims);

  k_reduce<<<(3 * NDST) / 256, 256, 0, stream>>>(sims, red);
  k_final<<<1, 1, 0, stream>>>(red, out);
}

// Round 6
// 288.466 us; speedup vs baseline: 1.4004x; 1.4004x over previous
//
#include <hip/hip_runtime.h>
#include <math.h>

#define NSRC 32768
#define NTOT 65536
#define NDST 32768
#define DH   256

typedef __attribute__((ext_vector_type(8))) short bf16x8;
typedef __attribute__((ext_vector_type(4))) float f32x4;

__device__ __forceinline__ float wave_reduce(float v) {
#pragma unroll
  for (int off = 32; off > 0; off >>= 1) v += __shfl_xor(v, off, 64);
  return v;
}
__device__ __forceinline__ unsigned short f2bf(float f) {
  union { float f; unsigned u; } v; v.f = f;
  unsigned r = v.u + 0x7FFFu + ((v.u >> 16) & 1u);
  return (unsigned short)(r >> 16);
}
__device__ __forceinline__ float bf2f(unsigned short h) {
  union { unsigned u; float f; } v; v.u = ((unsigned)h) << 16;
  return v.f;
}
__device__ __forceinline__ float4 bf4(ushort4 v) {
  return make_float4(bf2f(v.x), bf2f(v.y), bf2f(v.z), bf2f(v.w));
}
__device__ __forceinline__ void add4(float4& a, const float4 v) {
  a.x += v.x; a.y += v.y; a.z += v.z; a.w += v.w;
}
__device__ __forceinline__ float dot4(const float4 a, const float4 b) {
  return a.x * b.x + a.y * b.y + a.z * b.z + a.w * b.w;
}
// hsrc value: prelu(v + b) * isc
__device__ __forceinline__ float4 hsrc4(const float4 v, const float4 bv,
                                        float alpha, float isc) {
  float4 h;
  h.x = v.x + bv.x; h.x = (h.x >= 0.f ? h.x : alpha * h.x) * isc;
  h.y = v.y + bv.y; h.y = (h.y >= 0.f ? h.y : alpha * h.y) * isc;
  h.z = v.z + bv.z; h.z = (h.z >= 0.f ? h.z : alpha * h.z) * isc;
  h.w = v.w + bv.w; h.w = (h.w >= 0.f ? h.w : alpha * h.w) * isc;
  return h;
}

// ---------------- W -> Wt (transpose + bf16) --------------------------------
__global__ __launch_bounds__(256) void k_cvtW(const float* __restrict__ W,
                                              unsigned short* __restrict__ Wt) {
  const int n = blockIdx.x, k = threadIdx.x;
  Wt[n * 256 + k] = f2bf(W[(size_t)k * 256 + n]);
}

// ---------------- MFMA GEMM, N-split x2 for occupancy -----------------------
__global__ __launch_bounds__(256) void k_gemm_mfma(
    const float* __restrict__ A, const unsigned short* __restrict__ Wt,
    unsigned short* __restrict__ mb) {
  const int bid = blockIdx.x;
  const int rowgrp = (bid & 7) | ((bid >> 4) << 3);
  const int nhalf = (bid >> 3) & 1;
  const int t = threadIdx.x;
  const int lane = t & 63;
  const int wv = t >> 6;
  const int ln = lane & 15;
  const int kq = lane >> 4;          // 0..3
  const int row = rowgrp * 64 + wv * 16 + ln;

  bf16x8 bs[8];
  const float* ap = A + (size_t)row * 256 + kq * 8;
#pragma unroll
  for (int ks = 0; ks < 8; ++ks) {
    float4 a0 = *(const float4*)(ap + ks * 32);
    float4 a1 = *(const float4*)(ap + ks * 32 + 4);
    bf16x8 v;
    v[0] = (short)f2bf(a0.x); v[1] = (short)f2bf(a0.y);
    v[2] = (short)f2bf(a0.z); v[3] = (short)f2bf(a0.w);
    v[4] = (short)f2bf(a1.x); v[5] = (short)f2bf(a1.y);
    v[6] = (short)f2bf(a1.z); v[7] = (short)f2bf(a1.w);
    bs[ks] = v;
  }

  f32x4 acc[8];
#pragma unroll
  for (int i = 0; i < 8; ++i) acc[i] = (f32x4){0.f, 0.f, 0.f, 0.f};

  const int nt0 = nhalf * 8;
#pragma unroll
  for (int nt = 0; nt < 8; ++nt) {
    const unsigned short* wp = Wt + (size_t)((nt0 + nt) * 16 + ln) * 256 + kq * 8;
#pragma unroll
    for (int ks = 0; ks < 8; ++ks) {
      bf16x8 af = *(const bf16x8*)(wp + ks * 32);
      acc[nt] = __builtin_amdgcn_mfma_f32_16x16x32_bf16(af, bs[ks], acc[nt], 0, 0, 0);
    }
  }

  const int n0 = kq * 4;
#pragma unroll
  for (int nt = 0; nt < 8; ++nt) {
    ushort4 o;
    o.x = f2bf(acc[nt][0]); o.y = f2bf(acc[nt][1]);
    o.z = f2bf(acc[nt][2]); o.w = f2bf(acc[nt][3]);
    *(ushort4*)(mb + (size_t)row * 256 + (nt0 + nt) * 16 + n0) = o;
  }
}

// ---------------- per-src-row inverse norm of prelu(m+b) --------------------
__global__ __launch_bounds__(256) void k_inn(const unsigned short* __restrict__ mb,
                                             const float* __restrict__ b,
                                             const float* __restrict__ pa,
                                             float* __restrict__ inn) {
  const int row = blockIdx.x * 4 + (threadIdx.x >> 6);
  const int lane = threadIdx.x & 63;
  const int c = lane * 4;
  float4 v = bf4(*(const ushort4*)(mb + (size_t)row * 256 + c));
  float4 bv = *(const float4*)(b + c);
  const float alpha = pa[0];
  float4 h = hsrc4(v, bv, alpha, 1.0f);
  float ss = wave_reduce(dot4(h, h));
  if (lane == 0) inn[row] = 1.0f / fmaxf(sqrtf(ss), 1e-8f);
}

// ---------------- CSR build (pos graph only) --------------------------------
__global__ __launch_bounds__(256) void k_deg(const int* __restrict__ dst,
                                             int* __restrict__ deg, int nE) {
  const int e = blockIdx.x * 256 + threadIdx.x;
  if (e < nE) atomicAdd(&deg[dst[e] - NSRC], 1);
}

__global__ __launch_bounds__(256) void k_scan(const int* __restrict__ deg,
                                              int* __restrict__ rowStart) {
  __shared__ int tot[256];
  const int t = threadIdx.x;
  const int base = t * 128;
  int s = 0;
  for (int i = 0; i < 128; ++i) s += deg[base + i];
  tot[t] = s;
  __syncthreads();
  for (int off = 1; off < 256; off <<= 1) {
    int v = (t >= off) ? tot[t - off] : 0;
    __syncthreads();
    tot[t] += v;
    __syncthreads();
  }
  int pre = (t == 0) ? 0 : tot[t - 1];
  for (int i = 0; i < 128; ++i) {
    rowStart[base + i] = pre;
    pre += deg[base + i];
  }
  if (t == 255) rowStart[NDST] = pre;
}

__global__ __launch_bounds__(256) void k_fill(const int* __restrict__ src,
                                              const int* __restrict__ dst,
                                              const int* __restrict__ rowStart,
                                              int* __restrict__ cur,
                                              int* __restrict__ eSrc, int nE) {
  const int e = blockIdx.x * 256 + threadIdx.x;
  if (e >= nE) return;
  const int d = dst[e] - NSRC;
  const int p = atomicAdd(&cur[d], 1);
  eSrc[rowStart[d] + p] = src[e];
}

// ---------------- parallel claim: one thread per NEG edge, CAS matching -----
// neg edges are a sub-multiset of pos edges per row; greedy CAS is exact.
__global__ __launch_bounds__(256) void k_claim(const int* __restrict__ nsrc,
                                               const int* __restrict__ ndst,
                                               const int* __restrict__ rsP,
                                               const int* __restrict__ esP,
                                               int* __restrict__ claim, int nEn) {
  const int i = blockIdx.x * 256 + threadIdx.x;
  if (i >= nEn) return;
  const int d = ndst[i] - NSRC;
  const int s = nsrc[i];
  const int p1 = rsP[d + 1];
  for (int j = rsP[d]; j < p1; ++j) {
    if (esP[j] == s) {
      if (atomicCAS(&claim[j], 0, 1) == 0) return;
    }
  }
}

// ---------------- fused: agg(P,N) + prelu + norm + all loss terms -----------
__global__ __launch_bounds__(256) void k_fused(const unsigned short* __restrict__ mb,
                                               const float* __restrict__ inn,
                                               const int* __restrict__ rsP,
                                               const int* __restrict__ esP,
                                               const int* __restrict__ claim,
                                               const int* __restrict__ degN,
                                               const float* __restrict__ b,
                                               const float* __restrict__ pa,
                                               float* __restrict__ hraw,
                                               float* __restrict__ sims) {
  const int row = blockIdx.x * 4 + (threadIdx.x >> 6);
  const int lane = threadIdx.x & 63;
  const int c = lane * 4;
  const int p0 = rsP[row], p1 = rsP[row + 1];
  const int cN = degN[row];
  const float4 bv = *(const float4*)(b + c);
  const float alpha = pa[0];

  float4 self = bf4(*(const ushort4*)(mb + (size_t)(NSRC + row) * 256 + c));
  float4 aP0 = self, aP1 = {0.f, 0.f, 0.f, 0.f};
  float4 aN0 = self, aN1 = {0.f, 0.f, 0.f, 0.f};
  float4 sP0 = {0.f, 0.f, 0.f, 0.f}, sP1 = {0.f, 0.f, 0.f, 0.f};
  float4 sN0 = {0.f, 0.f, 0.f, 0.f}, sN1 = {0.f, 0.f, 0.f, 0.f};

  int e = p0;
  for (; e + 1 < p1; e += 2) {
    const int s0 = esP[e], s1 = esP[e + 1];
    const int cl0 = claim[e], cl1 = claim[e + 1];
    const float i0 = inn[s0], i1 = inn[s1];
    float4 v0 = bf4(*(const ushort4*)(mb + (size_t)s0 * 256 + c));
    float4 v1 = bf4(*(const ushort4*)(mb + (size_t)s1 * 256 + c));
    float4 h0 = hsrc4(v0, bv, alpha, i0);
    float4 h1 = hsrc4(v1, bv, alpha, i1);
    add4(aP0, v0); add4(sP0, h0);
    add4(aP1, v1); add4(sP1, h1);
    if (cl0) { add4(aN0, v0); add4(sN0, h0); }
    if (cl1) { add4(aN1, v1); add4(sN1, h1); }
  }
  if (e < p1) {
    const int s0 = esP[e];
    const int cl0 = claim[e];
    const float i0 = inn[s0];
    float4 v0 = bf4(*(const ushort4*)(mb + (size_t)s0 * 256 + c));
    float4 h0 = hsrc4(v0, bv, alpha, i0);
    add4(aP0, v0); add4(sP0, h0);
    if (cl0) { add4(aN0, v0); add4(sN0, h0); }
  }
  add4(aP0, aP1); add4(aN0, aN1); add4(sP0, sP1); add4(sN0, sN1);

  const float invP = 1.0f / (float)(p1 - p0 + 1);
  const float invN = 1.0f / (float)(cN + 1);
  float4 hp, hn;
  hp.x = aP0.x * invP + bv.x; hp.x = hp.x >= 0.f ? hp.x : alpha * hp.x;
  hp.y = aP0.y * invP + bv.y; hp.y = hp.y >= 0.f ? hp.y : alpha * hp.y;
  hp.z = aP0.z * invP + bv.z; hp.z = hp.z >= 0.f ? hp.z : alpha * hp.z;
  hp.w = aP0.w * invP + bv.w; hp.w = hp.w >= 0.f ? hp.w : alpha * hp.w;
  hn.x = aN0.x * invN + bv.x; hn.x = hn.x >= 0.f ? hn.x : alpha * hn.x;
  hn.y = aN0.y * invN + bv.y; hn.y = hn.y >= 0.f ? hn.y : alpha * hn.y;
  hn.z = aN0.z * invN + bv.z; hn.z = hn.z >= 0.f ? hn.z : alpha * hn.z;
  hn.w = aN0.w * invN + bv.w; hn.w = hn.w >= 0.f ? hn.w : alpha * hn.w;

  *(float4*)(hraw + (size_t)row * 256 + c) = hp;  // h_pos[NSRC:] output

  float ssP = wave_reduce(dot4(hp, hp));
  float ssN = wave_reduce(dot4(hn, hn));
  const float iP = 1.0f / fmaxf(sqrtf(ssP), 1e-8f);
  const float iN = 1.0f / fmaxf(sqrtf(ssN), 1e-8f);
  float4 xp = hp, xn = hn;
  xp.x *= iP; xp.y *= iP; xp.z *= iP; xp.w *= iP;
  xn.x *= iN; xn.y *= iN; xn.z *= iN; xn.w *= iN;

  float pos = wave_reduce(dot4(xp, xn));
  float n1 = wave_reduce(dot4(xp, sN0));
  float n2 = wave_reduce(dot4(xn, sP0));
  if (lane == 0) {
    sims[row] = pos;
    sims[NDST + row] = pos + n1;       // + self-loop term
    sims[2 * NDST + row] = pos + n2;   // + self-loop term
  }
}

// ---------------- final log-sum-exp reduce ----------------------------------
__global__ __launch_bounds__(256) void k_reduce(const float* __restrict__ sims,
                                                float* __restrict__ red) {
  const int i = blockIdx.x * 256 + threadIdx.x;
  const float v = sims[i];
  float e = expf(v);
  float p = (i < NDST) ? v : 0.f;
  e = wave_reduce(e);
  p = wave_reduce(p);
  __shared__ float se[4], sp[4];
  const int lane = threadIdx.x & 63, w = threadIdx.x >> 6;
  if (lane == 0) { se[w] = e; sp[w] = p; }
  __syncthreads();
  if (threadIdx.x == 0) {
    atomicAdd(red + 0, se[0] + se[1] + se[2] + se[3]);
    atomicAdd(red + 1, sp[0] + sp[1] + sp[2] + sp[3]);
  }
}

__global__ void k_final(const float* __restrict__ red, float* __restrict__ out) {
  out[0] = logf(red[0]) - red[1];
}

extern "C" void kernel_launch(void* const* d_in, const int* in_sizes, int n_in,
                              void* d_out, int out_size, void* d_ws, size_t ws_size,
                              hipStream_t stream) {
  const float* feat = (const float*)d_in[0];
  const int*   src  = (const int*)d_in[1];
  const int*   dst  = (const int*)d_in[2];
  const int*   nsrc = (const int*)d_in[3];
  const int*   ndst = (const int*)d_in[4];
  const float* W    = (const float*)d_in[5];
  const float* b    = (const float*)d_in[6];
  const float* pa   = (const float*)d_in[7];
  const int nE  = in_sizes[1];
  const int nEn = in_sizes[3];
  float* out = (float*)d_out;

  unsigned short* mb = (unsigned short*)d_ws;            // NTOT*256 bf16
  unsigned short* Wt = mb + (size_t)NTOT * 256;          // 256*256 bf16
  float* inn  = (float*)(Wt + 256 * 256);                // NSRC
  float* sims = inn + NSRC;                              // 3*NDST
  float* red  = sims + 3 * (size_t)NDST;                 // 8
  int* degP  = (int*)(red + 8);                          // NDST
  int* curP  = degP + NDST;                              // NDST
  int* degN  = curP + NDST;                              // NDST
  int* rsP   = degN + NDST;                              // NDST+1
  int* eSrcP = rsP + NDST + 1;                           // nE
  int* claim = eSrcP + nE;                               // nE ints

  hipMemsetAsync(degP, 0, 3 * (size_t)NDST * sizeof(int), stream);
  hipMemsetAsync(claim, 0, (size_t)nE * sizeof(int), stream);
  hipMemsetAsync(red, 0, 8 * sizeof(float), stream);

  k_cvtW<<<256, 256, 0, stream>>>(W, Wt);
  k_gemm_mfma<<<2048, 256, 0, stream>>>(feat, Wt, mb);
  k_inn<<<NSRC / 4, 256, 0, stream>>>(mb, b, pa, inn);

  k_deg<<<(nE + 255) / 256, 256, 0, stream>>>(dst, degP, nE);
  k_deg<<<(nEn + 255) / 256, 256, 0, stream>>>(ndst, degN, nEn);
  k_scan<<<1, 256, 0, stream>>>(degP, rsP);
  k_fill<<<(nE + 255) / 256, 256, 0, stream>>>(src, dst, rsP, curP, eSrcP, nE);
  k_claim<<<(nEn + 255) / 256, 256, 0, stream>>>(nsrc, ndst, rsP, eSrcP, claim, nEn);

  k_fused<<<NDST / 4, 256, 0, stream>>>(mb, inn, rsP, eSrcP, claim, degN, b, pa,
                                        out + 1, sims);

  k_reduce<<<(3 * NDST) / 256, 256, 0, stream>>>(sims, red);
  k_final<<<1, 1, 0, stream>>>(red, out);
}